// Round 1
// baseline (321.727 us; speedup 1.0000x reference)
//
#include <hip/hip_runtime.h>

// Problem constants
#define D 512      // view dim / d_out
#define B 4096     // batch
#define R 32       // TT rank
#define AB 1024    // R*R rows of the reshaped core GEMM

// ---------------------------------------------------------------------------
// K1: repack core1/core2 [a][d][b] -> Apack[j][row=a*32+b][d] (contiguous in d)
// ---------------------------------------------------------------------------
__global__ __launch_bounds__(256) void repack_kernel(
    const float* __restrict__ c1, const float* __restrict__ c2,
    float* __restrict__ Apack)
{
    int idx = blockIdx.x * 256 + threadIdx.x;   // over 2*1024*512 = 1048576
    int j   = idx >> 19;                        // 524288 per view
    int rem = idx & 524287;
    int row = rem >> 9;                         // 0..1023
    int d   = rem & 511;
    int a   = row >> 5, b = row & 31;
    const float* c = j ? c2 : c1;
    Apack[idx] = c[a * (D * R) + d * R + b];
}

// ---------------------------------------------------------------------------
// K2: C_j[row][n] = sum_d Apack_j[row][d] * X_j[d][n]
//     classic fp32 tiled GEMM: BM=BN=64, BK=16, 256 threads, 4x4/thread
// ---------------------------------------------------------------------------
#define BK 16
__global__ __launch_bounds__(256) void gemm_view(
    const float* __restrict__ Apack, const float* __restrict__ X0,
    const float* __restrict__ X1, float* __restrict__ M)
{
    const int j = blockIdx.z;
    const float* __restrict__ A = Apack + (size_t)j * AB * D;
    const float* __restrict__ X = j ? X1 : X0;
    float* __restrict__ C = M + (size_t)j * AB * B;

    __shared__ float As[BK][64];   // [k][row]  (transposed for b128 frag reads)
    __shared__ float Bs[BK][64];   // [k][n]

    const int tid = threadIdx.x;
    const int tx = tid & 15, ty = tid >> 4;
    const int rowBase = blockIdx.y * 64, colBase = blockIdx.x * 64;

    const int ar = tid >> 2;          // 0..63 A-row within tile
    const int ak = (tid & 3) << 2;    // 0,4,8,12 k offset
    const int bk = tid >> 4;          // 0..15 k row of X tile
    const int bn = (tid & 15) << 2;   // 0..60 n offset

    float acc[4][4] = {};

    for (int k0 = 0; k0 < D; k0 += BK) {
        float4 av = *reinterpret_cast<const float4*>(
            &A[(size_t)(rowBase + ar) * D + k0 + ak]);
        float4 bv = *reinterpret_cast<const float4*>(
            &X[(size_t)(k0 + bk) * B + colBase + bn]);
        As[ak + 0][ar] = av.x;
        As[ak + 1][ar] = av.y;
        As[ak + 2][ar] = av.z;
        As[ak + 3][ar] = av.w;
        *reinterpret_cast<float4*>(&Bs[bk][bn]) = bv;
        __syncthreads();
#pragma unroll
        for (int k = 0; k < BK; ++k) {
            float4 a4 = *reinterpret_cast<const float4*>(&As[k][ty << 2]);
            float4 b4 = *reinterpret_cast<const float4*>(&Bs[k][tx << 2]);
            float aa[4] = {a4.x, a4.y, a4.z, a4.w};
            float bb[4] = {b4.x, b4.y, b4.z, b4.w};
#pragma unroll
            for (int i = 0; i < 4; ++i)
#pragma unroll
                for (int jj = 0; jj < 4; ++jj)
                    acc[i][jj] += aa[i] * bb[jj];
        }
        __syncthreads();
    }
#pragma unroll
    for (int i = 0; i < 4; ++i) {
        float4 o = make_float4(acc[i][0], acc[i][1], acc[i][2], acc[i][3]);
        *reinterpret_cast<float4*>(
            &C[(size_t)(rowBase + (ty << 2) + i) * B + colBase + (tx << 2)]) = o;
    }
}

// ---------------------------------------------------------------------------
// K3: m2[c][n] = sum_d core3[c][d] * X2[d][n]   (core3 is [32][512] contiguous)
// ---------------------------------------------------------------------------
__global__ __launch_bounds__(512) void m2_kernel(
    const float* __restrict__ X2, const float* __restrict__ core3,
    float* __restrict__ m2buf)
{
    const int tid = threadIdx.x;
    const int n = blockIdx.x * 64 + (tid & 63);
    const int q = tid >> 6;          // 0..7 -> 4 c's each
    float acc[4] = {};
    for (int d = 0; d < D; ++d) {
        float x = X2[(size_t)d * B + n];
#pragma unroll
        for (int cc = 0; cc < 4; ++cc)
            acc[cc] += core3[(q * 4 + cc) * D + d] * x;
    }
#pragma unroll
    for (int cc = 0; cc < 4; ++cc)
        m2buf[(size_t)(q * 4 + cc) * B + n] = acc[cc];
}

// ---------------------------------------------------------------------------
// K4: per-sample chain + output.
//   t[b] = sum_c M1[b][c][n]*m2[c];  z[a] = sum_b M0[a][b][n]*t[b];
//   Z[d][n] = sum_a core0[d][a]*z[a]
//   block = 32 columns of n, 256 threads (n = tid&31, q = tid>>5 in 0..7)
// ---------------------------------------------------------------------------
__global__ __launch_bounds__(256) void chain_kernel(
    const float* __restrict__ M, const float* __restrict__ m2buf,
    const float* __restrict__ core0, float* __restrict__ out)
{
    __shared__ float m2s[R][32];
    __shared__ float ts[R][32];
    __shared__ float zs[R][32];

    const float* __restrict__ M0 = M;
    const float* __restrict__ M1 = M + (size_t)AB * B;

    const int tid = threadIdx.x;
    const int n0 = blockIdx.x * 32;
    const int n = tid & 31, q = tid >> 5;   // q in 0..7

    // stage m2 tile [32][32]
#pragma unroll
    for (int i = 0; i < 4; ++i) {
        int l = tid + i * 256;
        m2s[l >> 5][l & 31] = m2buf[(size_t)(l >> 5) * B + n0 + (l & 31)];
    }
    __syncthreads();

    // phase 1: t[b][n]
#pragma unroll
    for (int bb = 0; bb < 4; ++bb) {
        int b = q * 4 + bb;
        float acc = 0.f;
#pragma unroll
        for (int c = 0; c < R; ++c)
            acc += M1[(size_t)(b * R + c) * B + n0 + n] * m2s[c][n];
        ts[b][n] = acc;
    }
    __syncthreads();

    // phase 2: z[a][n]
#pragma unroll
    for (int aa = 0; aa < 4; ++aa) {
        int a = q * 4 + aa;
        float acc = 0.f;
#pragma unroll
        for (int b = 0; b < R; ++b)
            acc += M0[(size_t)(a * R + b) * B + n0 + n] * ts[b][n];
        zs[a][n] = acc;
    }
    __syncthreads();

    // phase 3: Z[d][n] for d = q + 8*i
    float zcol[R];
#pragma unroll
    for (int a = 0; a < R; ++a) zcol[a] = zs[a][n];

    for (int i = 0; i < 64; ++i) {
        int d = q + i * 8;
        float acc = 0.f;
#pragma unroll
        for (int a = 0; a < R; ++a)
            acc += core0[d * R + a] * zcol[a];
        out[(size_t)d * B + n0 + n] = acc;
    }
}

// ---------------------------------------------------------------------------
extern "C" void kernel_launch(void* const* d_in, const int* in_sizes, int n_in,
                              void* d_out, int out_size, void* d_ws, size_t ws_size,
                              hipStream_t stream)
{
    const float* X0    = (const float*)d_in[0];
    const float* X1    = (const float*)d_in[1];
    const float* X2    = (const float*)d_in[2];
    const float* core0 = (const float*)d_in[3];
    const float* core1 = (const float*)d_in[4];
    const float* core2 = (const float*)d_in[5];
    const float* core3 = (const float*)d_in[6];
    float* out = (float*)d_out;

    float* ws     = (float*)d_ws;
    float* Apack  = ws;                          // 2*1024*512  = 1,048,576 f
    float* M      = ws + 1048576;                // 2*1024*4096 = 8,388,608 f
    float* m2buf  = ws + 1048576 + 8388608;      // 32*4096     =   131,072 f

    hipLaunchKernelGGL(repack_kernel, dim3(4096), dim3(256), 0, stream,
                       core1, core2, Apack);
    hipLaunchKernelGGL(gemm_view, dim3(B / 64, AB / 64, 2), dim3(256), 0, stream,
                       Apack, X0, X1, M);
    hipLaunchKernelGGL(m2_kernel, dim3(B / 64), dim3(512), 0, stream,
                       X2, core3, m2buf);
    hipLaunchKernelGGL(chain_kernel, dim3(B / 32), dim3(256), 0, stream,
                       M, m2buf, core0, out);
}

// Round 2
// 196.986 us; speedup vs baseline: 1.6332x; 1.6332x over previous
//
#include <hip/hip_runtime.h>

#define D 512      // view dim / d_out
#define B 4096     // batch
#define R 32       // TT rank
#define AB 1024    // R*R rows of reshaped core GEMM

typedef unsigned short ushort_t;
typedef __attribute__((ext_vector_type(8))) short bf16x8;
typedef __attribute__((ext_vector_type(4))) float f32x4;

__device__ __forceinline__ ushort_t f2bf(float f) {
  uint32_t u = __builtin_bit_cast(uint32_t, f);
  u = (u + 0x7FFFu + ((u >> 16) & 1u)) >> 16;   // RNE
  return (ushort_t)u;
}
__device__ __forceinline__ float bf2f(ushort_t h) {
  uint32_t u = ((uint32_t)h) << 16;
  return __builtin_bit_cast(float, u);
}
__device__ __forceinline__ void gload_lds16(const void* g, void* lds) {
  __builtin_amdgcn_global_load_lds(
      (const __attribute__((address_space(1))) unsigned int*)g,
      (__attribute__((address_space(3))) unsigned int*)lds, 16, 0, 0);
}

// ---------------------------------------------------------------------------
// K1: cores [a][d][b] fp32 -> Apack[j][a*32+b][d] bf16 (d contiguous)
// one block per (j,a); LDS transpose for coalesced read AND write
// ---------------------------------------------------------------------------
__global__ __launch_bounds__(256) void pack_cores(
    const float* __restrict__ c1, const float* __restrict__ c2,
    ushort_t* __restrict__ Apack)
{
  __shared__ ushort_t T[R][D + 8];
  const int ja = blockIdx.x, j = ja >> 5, a = ja & 31;
  const float* __restrict__ c = j ? c2 : c1;
  const int tid = threadIdx.x;
#pragma unroll
  for (int i = 0; i < 64; ++i) {
    int e = i * 256 + tid;                 // e = d*32 + b, coalesced source
    T[e & 31][e >> 5] = f2bf(c[(size_t)a * (D * R) + e]);
  }
  __syncthreads();
#pragma unroll
  for (int i = 0; i < 8; ++i) {
    int ch = i * 256 + tid;                // 2048 16B chunks
    int b = ch >> 6, off = (ch & 63) * 8;
    ushort_t v[8];
#pragma unroll
    for (int q = 0; q < 8; ++q) v[q] = T[b][off + q];
    *(bf16x8*)&Apack[((size_t)j * AB + a * 32 + b) * D + off] = *(bf16x8*)v;
  }
}

// ---------------------------------------------------------------------------
// K2: X fp32 [d][n] -> Xt bf16 [j][n][d]  (tiled transpose + convert)
// ---------------------------------------------------------------------------
__global__ __launch_bounds__(256) void transpose_x(
    const float* __restrict__ X0, const float* __restrict__ X1,
    ushort_t* __restrict__ Xt)
{
  __shared__ float T[64][65];
  const int j = blockIdx.z;
  const float* __restrict__ X = j ? X1 : X0;
  ushort_t* __restrict__ O = Xt + (size_t)j * B * D;
  const int n0 = blockIdx.x * 64, d0 = blockIdx.y * 64;
  const int tid = threadIdx.x;
#pragma unroll
  for (int i = 0; i < 16; ++i) {
    int e = i * 256 + tid;
    T[e >> 6][e & 63] = X[(size_t)(d0 + (e >> 6)) * B + n0 + (e & 63)];
  }
  __syncthreads();
#pragma unroll
  for (int i = 0; i < 2; ++i) {
    int ch = i * 256 + tid;                // 512 chunks
    int nr = ch >> 3, dc = (ch & 7) * 8;
    ushort_t v[8];
#pragma unroll
    for (int q = 0; q < 8; ++q) v[q] = f2bf(T[dc + q][nr]);
    *(bf16x8*)&O[(size_t)(n0 + nr) * D + d0 + dc] = *(bf16x8*)v;
  }
}

// ---------------------------------------------------------------------------
// K3: M_j[row][n] = sum_d A_j[row][d] * Xt_j[n][d]   (bf16 MFMA 16x16x32)
// 128x128 tile, BK=32, 4 waves (2x2), double-buffered global_load_lds,
// XOR-swizzled LDS (inverse-swizzle on SOURCE, swizzle on ds_read).
// ---------------------------------------------------------------------------
__global__ __launch_bounds__(256) void gemm_mfma(
    const ushort_t* __restrict__ Apack, const ushort_t* __restrict__ Xt,
    ushort_t* __restrict__ Mout)
{
  __shared__ __align__(16) ushort_t As[2][4096];   // [buf][128 rows][32 k]
  __shared__ __align__(16) ushort_t Bs[2][4096];

  const int j = blockIdx.z;
  const ushort_t* __restrict__ A  = Apack + (size_t)j * AB * D;
  const ushort_t* __restrict__ Bt = Xt + (size_t)j * B * D;
  ushort_t* __restrict__ C = Mout + (size_t)j * AB * B;

  const int tid = threadIdx.x;
  const int lane = tid & 63, wid = tid >> 6;
  const int wr = wid >> 1, wc = wid & 1;
  const int rowBase = blockIdx.y * 128, colBase = blockIdx.x * 128;

  // staging: unit t covers LDS 16B unit t -> (row=t>>2, slot u'=t&3),
  // source k-unit u = u' ^ (row&3)  (involution)
  const int t0 = wid * 128 + lane, t1 = t0 + 64;
  const int r0 = t0 >> 2, u0 = (t0 & 3) ^ (r0 & 3);
  const int r1 = t1 >> 2, u1 = (t1 & 3) ^ (r1 & 3);
  const ushort_t* gA0 = A + (size_t)(rowBase + r0) * D + u0 * 8;
  const ushort_t* gA1 = A + (size_t)(rowBase + r1) * D + u1 * 8;
  const ushort_t* gB0 = Bt + (size_t)(colBase + r0) * D + u0 * 8;
  const ushort_t* gB1 = Bt + (size_t)(colBase + r1) * D + u1 * 8;
  const int ldsq0 = wid * 1024, ldsq1 = wid * 1024 + 512;  // element offsets

  // frag read offsets (loop-invariant): logical (row, u=lane>>4) -> slot u^(row&3)
  int aoff[4], boff[4];
#pragma unroll
  for (int m = 0; m < 4; ++m) {
    int row = wr * 64 + m * 16 + (lane & 15);
    aoff[m] = row * 32 + (((lane >> 4) ^ (row & 3)) * 8);
  }
#pragma unroll
  for (int n = 0; n < 4; ++n) {
    int col = wc * 64 + n * 16 + (lane & 15);
    boff[n] = col * 32 + (((lane >> 4) ^ (col & 3)) * 8);
  }

  f32x4 acc[4][4] = {};

  // prologue: stage k-tile 0 into buf 0
  gload_lds16(gA0, &As[0][ldsq0]);
  gload_lds16(gA1, &As[0][ldsq1]);
  gload_lds16(gB0, &Bs[0][ldsq0]);
  gload_lds16(gB1, &Bs[0][ldsq1]);
  __syncthreads();

  int buf = 0;
  for (int kt = 0; kt < 16; ++kt) {
    if (kt < 15) {
      int k0 = (kt + 1) * 32;
      gload_lds16(gA0 + k0, &As[buf ^ 1][ldsq0]);
      gload_lds16(gA1 + k0, &As[buf ^ 1][ldsq1]);
      gload_lds16(gB0 + k0, &Bs[buf ^ 1][ldsq0]);
      gload_lds16(gB1 + k0, &Bs[buf ^ 1][ldsq1]);
    }
    bf16x8 a[4], b[4];
#pragma unroll
    for (int m = 0; m < 4; ++m) a[m] = *(const bf16x8*)&As[buf][aoff[m]];
#pragma unroll
    for (int n = 0; n < 4; ++n) b[n] = *(const bf16x8*)&Bs[buf][boff[n]];
#pragma unroll
    for (int m = 0; m < 4; ++m)
#pragma unroll
      for (int n = 0; n < 4; ++n)
        acc[m][n] = __builtin_amdgcn_mfma_f32_16x16x32_bf16(a[m], b[n], acc[m][n], 0, 0, 0);
    __syncthreads();    // drains vmcnt (stage) + lgkm (frag reads) per wave
    buf ^= 1;
  }

  // epilogue: C/D layout col=lane&15, row=(lane>>4)*4+reg  [m89-verified]
#pragma unroll
  for (int m = 0; m < 4; ++m) {
#pragma unroll
    for (int n = 0; n < 4; ++n) {
      int row0 = rowBase + wr * 64 + m * 16 + ((lane >> 4) << 2);
      int col  = colBase + wc * 64 + n * 16 + (lane & 15);
#pragma unroll
      for (int r = 0; r < 4; ++r)
        C[(size_t)(row0 + r) * B + col] = f2bf(acc[m][n][r]);
    }
  }
}

// ---------------------------------------------------------------------------
// K4: m2[c][n] = sum_d core3[c][d] * X2[d][n]   (fp32, tiny)
// ---------------------------------------------------------------------------
__global__ __launch_bounds__(256) void m2_kernel(
    const float* __restrict__ X2, const float* __restrict__ core3,
    float* __restrict__ m2buf)
{
  const int tid = threadIdx.x;
  const int n = blockIdx.x * 32 + (tid & 31);
  const int q = tid >> 5;
  float acc[4] = {};
  for (int d = 0; d < D; ++d) {
    float x = X2[(size_t)d * B + n];
#pragma unroll
    for (int cc = 0; cc < 4; ++cc)
      acc[cc] += core3[(q * 4 + cc) * D + d] * x;
  }
#pragma unroll
  for (int cc = 0; cc < 4; ++cc)
    m2buf[(size_t)(q * 4 + cc) * B + n] = acc[cc];
}

// ---------------------------------------------------------------------------
// K5: per-sample chain: t = M1*m2 ; z = M0*t  -> zbuf[32][B]  (M is bf16)
// ---------------------------------------------------------------------------
__global__ __launch_bounds__(256) void chain_kernel(
    const ushort_t* __restrict__ M, const float* __restrict__ m2buf,
    float* __restrict__ zbuf)
{
  __shared__ float m2s[R][32];
  __shared__ float ts[R][32];
  const ushort_t* __restrict__ M0 = M;
  const ushort_t* __restrict__ M1 = M + (size_t)AB * B;
  const int tid = threadIdx.x;
  const int n0 = blockIdx.x * 32;
  const int n = tid & 31, q = tid >> 5;
#pragma unroll
  for (int i = 0; i < 4; ++i) {
    int l = tid + i * 256;
    m2s[l >> 5][l & 31] = m2buf[(size_t)(l >> 5) * B + n0 + (l & 31)];
  }
  __syncthreads();
#pragma unroll
  for (int bb = 0; bb < 4; ++bb) {
    int b = q * 4 + bb;
    float acc = 0.f;
#pragma unroll
    for (int c = 0; c < R; ++c)
      acc += bf2f(M1[(size_t)(b * R + c) * B + n0 + n]) * m2s[c][n];
    ts[b][n] = acc;
  }
  __syncthreads();
#pragma unroll
  for (int aa = 0; aa < 4; ++aa) {
    int a = q * 4 + aa;
    float acc = 0.f;
#pragma unroll
    for (int b = 0; b < R; ++b)
      acc += bf2f(M0[(size_t)(a * R + b) * B + n0 + n]) * ts[b][n];
    zbuf[(size_t)a * B + n0 + n] = acc;
  }
}

// ---------------------------------------------------------------------------
// K6: Z[d][n] = sum_a core0[d][a] * zbuf[a][n]   (fp32, K=32)
// ---------------------------------------------------------------------------
__global__ __launch_bounds__(256) void zgemm(
    const float* __restrict__ zbuf, const float* __restrict__ core0,
    float* __restrict__ out)
{
  __shared__ float c0s[64][R];
  __shared__ float zs[R][128];
  const int n0 = blockIdx.x * 128, d0 = blockIdx.y * 64;
  const int tid = threadIdx.x;
#pragma unroll
  for (int i = 0; i < 4; ++i) {
    int ch = i * 256 + tid;               // 1024 float4 chunks of zs
    int rr = ch >> 5, off = (ch & 31) * 4;
    *(float4*)&zs[rr][off] = *(const float4*)&zbuf[(size_t)rr * B + n0 + off];
  }
#pragma unroll
  for (int i = 0; i < 2; ++i) {
    int ch = i * 256 + tid;               // 512 float4 chunks of core0 tile
    int rr = ch >> 3, off = (ch & 7) * 4;
    *(float4*)&c0s[rr][off] = *(const float4*)&core0[(size_t)(d0 + rr) * R + off];
  }
  __syncthreads();
  const int tx = tid & 31, ty = tid >> 5;
  float acc[8][4] = {};
  for (int k = 0; k < R; ++k) {
    float4 z4 = *(const float4*)&zs[k][tx * 4];
    float zz[4] = {z4.x, z4.y, z4.z, z4.w};
#pragma unroll
    for (int i = 0; i < 8; ++i) {
      float cv = c0s[ty * 8 + i][k];
#pragma unroll
      for (int jj = 0; jj < 4; ++jj) acc[i][jj] += cv * zz[jj];
    }
  }
#pragma unroll
  for (int i = 0; i < 8; ++i) {
    float4 o = {acc[i][0], acc[i][1], acc[i][2], acc[i][3]};
    *(float4*)&out[(size_t)(d0 + ty * 8 + i) * B + n0 + tx * 4] = o;
  }
}

// ---------------------------------------------------------------------------
extern "C" void kernel_launch(void* const* d_in, const int* in_sizes, int n_in,
                              void* d_out, int out_size, void* d_ws, size_t ws_size,
                              hipStream_t stream)
{
  const float* X0    = (const float*)d_in[0];
  const float* X1    = (const float*)d_in[1];
  const float* X2    = (const float*)d_in[2];
  const float* core0 = (const float*)d_in[3];
  const float* core1 = (const float*)d_in[4];
  const float* core2 = (const float*)d_in[5];
  const float* core3 = (const float*)d_in[6];
  float* out = (float*)d_out;

  char* ws = (char*)d_ws;
  ushort_t* Apack = (ushort_t*)(ws);                        //  2 MB
  ushort_t* Xt    = (ushort_t*)(ws + (2u << 20));           //  8 MB
  ushort_t* Mbuf  = (ushort_t*)(ws + (10u << 20));          // 16 MB
  float*    m2buf = (float*)   (ws + (26u << 20));          // 0.5 MB
  float*    zbuf  = (float*)   (ws + (27u << 20));          // 0.5 MB

  hipLaunchKernelGGL(pack_cores, dim3(64), dim3(256), 0, stream, core1, core2, Apack);
  hipLaunchKernelGGL(transpose_x, dim3(64, 8, 2), dim3(256), 0, stream, X0, X1, Xt);
  hipLaunchKernelGGL(gemm_mfma, dim3(32, 8, 2), dim3(256), 0, stream, Apack, Xt, Mbuf);
  hipLaunchKernelGGL(m2_kernel, dim3(128), dim3(256), 0, stream, X2, core3, m2buf);
  hipLaunchKernelGGL(chain_kernel, dim3(128), dim3(256), 0, stream, Mbuf, m2buf, zbuf);
  hipLaunchKernelGGL(zgemm, dim3(32, 8), dim3(256), 0, stream, zbuf, core0, out);
}

// Round 4
// 139.955 us; speedup vs baseline: 2.2988x; 1.4075x over previous
//
#include <hip/hip_runtime.h>

#define D 512      // view dim / d_out
#define B 4096     // batch
#define R 32       // TT rank
#define AB 1024    // R*R rows of reshaped core GEMM

typedef unsigned short ushort_t;
typedef __attribute__((ext_vector_type(8))) short bf16x8;
typedef __attribute__((ext_vector_type(4))) float f32x4;

__device__ __forceinline__ ushort_t f2bf(float f) {
  uint32_t u = __builtin_bit_cast(uint32_t, f);
  u = (u + 0x7FFFu + ((u >> 16) & 1u)) >> 16;   // RNE
  return (ushort_t)u;
}
__device__ __forceinline__ float bf2f(ushort_t h) {
  uint32_t u = ((uint32_t)h) << 16;
  return __builtin_bit_cast(float, u);
}
__device__ __forceinline__ void gload_lds16(const void* g, void* lds) {
  __builtin_amdgcn_global_load_lds(
      (const __attribute__((address_space(1))) unsigned int*)g,
      (__attribute__((address_space(3))) unsigned int*)lds, 16, 0, 0);
}

// ---------------------------------------------------------------------------
// K1: cores [a][d][b] fp32 -> Apack[j][a*32+b][d] bf16 (d contiguous)
// ---------------------------------------------------------------------------
__global__ __launch_bounds__(256) void pack_cores(
    const float* __restrict__ c1, const float* __restrict__ c2,
    ushort_t* __restrict__ Apack)
{
  __shared__ ushort_t T[R][D + 8];
  const int ja = blockIdx.x, j = ja >> 5, a = ja & 31;
  const float* __restrict__ c = j ? c2 : c1;
  const int tid = threadIdx.x;
#pragma unroll
  for (int i = 0; i < 64; ++i) {
    int e = i * 256 + tid;                 // e = d*32 + b, coalesced source
    T[e & 31][e >> 5] = f2bf(c[(size_t)a * (D * R) + e]);
  }
  __syncthreads();
#pragma unroll
  for (int i = 0; i < 8; ++i) {
    int ch = i * 256 + tid;                // 2048 16B chunks
    int b = ch >> 6, off = (ch & 63) * 8;
    ushort_t v[8];
#pragma unroll
    for (int q = 0; q < 8; ++q) v[q] = T[b][off + q];
    *(bf16x8*)&Apack[((size_t)j * AB + a * 32 + b) * D + off] = *(bf16x8*)v;
  }
}

// ---------------------------------------------------------------------------
// K2: X fp32 [d][n] -> Xt bf16 [j][n][d]  (tiled transpose + convert)
// ---------------------------------------------------------------------------
__global__ __launch_bounds__(256) void transpose_x(
    const float* __restrict__ X0, const float* __restrict__ X1,
    ushort_t* __restrict__ Xt)
{
  __shared__ float T[64][65];
  const int j = blockIdx.z;
  const float* __restrict__ X = j ? X1 : X0;
  ushort_t* __restrict__ O = Xt + (size_t)j * B * D;
  const int n0 = blockIdx.x * 64, d0 = blockIdx.y * 64;
  const int tid = threadIdx.x;
#pragma unroll
  for (int i = 0; i < 16; ++i) {
    int e = i * 256 + tid;
    T[e >> 6][e & 63] = X[(size_t)(d0 + (e >> 6)) * B + n0 + (e & 63)];
  }
  __syncthreads();
#pragma unroll
  for (int i = 0; i < 2; ++i) {
    int ch = i * 256 + tid;                // 512 chunks
    int nr = ch >> 3, dc = (ch & 7) * 8;
    ushort_t v[8];
#pragma unroll
    for (int q = 0; q < 8; ++q) v[q] = f2bf(T[dc + q][nr]);
    *(bf16x8*)&O[(size_t)(n0 + nr) * D + d0 + dc] = *(bf16x8*)v;
  }
}

// ---------------------------------------------------------------------------
// K3: Mt_j[n][row] = sum_d Xt_j[n][d] * A_j[row][d]   (bf16 MFMA 16x16x32)
// A-operand = Xt (n-dim), B-operand = Apack (row-dim) -> transposed output.
// 128x128 tile, BK=32, 4 waves, dbuf global_load_lds, XOR-swizzled LDS,
// LDS-staged epilogue for coalesced [n][row] stores.
// ---------------------------------------------------------------------------
__global__ __launch_bounds__(256) void gemm_mfma(
    const ushort_t* __restrict__ Apack, const ushort_t* __restrict__ Xt,
    ushort_t* __restrict__ Mt)
{
  __shared__ __align__(16) ushort_t smem[17408];   // 34.8 KB
  ushort_t* As0 = smem;            // Xt tile buf0: [128 n][32 k] swizzled
  ushort_t* As1 = smem + 4096;
  ushort_t* Bs0 = smem + 8192;     // Apack tile
  ushort_t* Bs1 = smem + 12288;

  const int j = blockIdx.z;
  const ushort_t* __restrict__ Ag = Xt + (size_t)j * B * D;      // [4096][512]
  const ushort_t* __restrict__ Bg = Apack + (size_t)j * AB * D;  // [1024][512]
  ushort_t* __restrict__ C = Mt + (size_t)j * B * AB;            // [n][row]

  const int tid = threadIdx.x;
  const int lane = tid & 63, wid = tid >> 6;
  const int wr = wid >> 1, wc = wid & 1;
  const int nBase = blockIdx.y * 128;   // over B=4096
  const int rBase = blockIdx.x * 128;   // over AB=1024

  // staging map: 16B unit t -> LDS (row=t>>2, slot u'=t&3); src u = u'^(row&3)
  const int t0 = wid * 128 + lane, t1 = t0 + 64;
  const int r0 = t0 >> 2, u0 = (t0 & 3) ^ (r0 & 3);
  const int r1 = t1 >> 2, u1 = (t1 & 3) ^ (r1 & 3);
  const ushort_t* gA0 = Ag + (size_t)(nBase + r0) * D + u0 * 8;
  const ushort_t* gA1 = Ag + (size_t)(nBase + r1) * D + u1 * 8;
  const ushort_t* gB0 = Bg + (size_t)(rBase + r0) * D + u0 * 8;
  const ushort_t* gB1 = Bg + (size_t)(rBase + r1) * D + u1 * 8;
  const int lq0 = wid * 1024, lq1 = wid * 1024 + 512;   // element offsets

  // frag read offsets: logical (row, u=lane>>4) -> slot u^(row&3)
  int aoff[4], boff[4];
#pragma unroll
  for (int m = 0; m < 4; ++m) {
    int row = wr * 64 + m * 16 + (lane & 15);
    aoff[m] = row * 32 + (((lane >> 4) ^ (row & 3)) * 8);
  }
#pragma unroll
  for (int n = 0; n < 4; ++n) {
    int col = wc * 64 + n * 16 + (lane & 15);
    boff[n] = col * 32 + (((lane >> 4) ^ (col & 3)) * 8);
  }

  f32x4 acc[4][4] = {};

  auto stage = [&](ushort_t* Asb, ushort_t* Bsb, int k0) {
    gload_lds16(gA0 + k0, Asb + lq0);
    gload_lds16(gA1 + k0, Asb + lq1);
    gload_lds16(gB0 + k0, Bsb + lq0);
    gload_lds16(gB1 + k0, Bsb + lq1);
  };
  auto compute = [&](const ushort_t* Asb, const ushort_t* Bsb) {
    bf16x8 a[4], b[4];
#pragma unroll
    for (int m = 0; m < 4; ++m) a[m] = *(const bf16x8*)&Asb[aoff[m]];
#pragma unroll
    for (int n = 0; n < 4; ++n) b[n] = *(const bf16x8*)&Bsb[boff[n]];
#pragma unroll
    for (int m = 0; m < 4; ++m)
#pragma unroll
      for (int n = 0; n < 4; ++n)
        acc[m][n] = __builtin_amdgcn_mfma_f32_16x16x32_bf16(a[m], b[n], acc[m][n], 0, 0, 0);
  };

  stage(As0, Bs0, 0);
  __syncthreads();
#pragma unroll 1
  for (int kp = 0; kp < 8; ++kp) {
    stage(As1, Bs1, kp * 64 + 32);        // prefetch odd tile
    compute(As0, Bs0);
    __syncthreads();
    if (kp < 7) stage(As0, Bs0, kp * 64 + 64);  // prefetch next even tile
    compute(As1, Bs1);
    __syncthreads();
  }

  // epilogue: acc -> LDS tile T[128 n][128 row] (pad 8) -> coalesced stores
#define TLD 136
  ushort_t* T = smem;
  const int qn = (lane >> 4) << 2;
#pragma unroll
  for (int m = 0; m < 4; ++m)
#pragma unroll
    for (int nn = 0; nn < 4; ++nn) {
      int nl = wr * 64 + m * 16 + qn;
      int rl = wc * 64 + nn * 16 + (lane & 15);
#pragma unroll
      for (int r = 0; r < 4; ++r)
        T[(nl + r) * TLD + rl] = f2bf(acc[m][nn][r]);
    }
  __syncthreads();
#pragma unroll
  for (int i = 0; i < 8; ++i) {
    int nl = i * 16 + (tid >> 4);
    int rl = (tid & 15) * 8;
    bf16x8 v = *(const bf16x8*)&T[nl * TLD + rl];
    *(bf16x8*)&C[(size_t)(nBase + nl) * AB + rBase + rl] = v;
  }
}

// ---------------------------------------------------------------------------
// K4: m2t[n][c] = sum_d core3[c][d] * X2[d][n]
// ---------------------------------------------------------------------------
__global__ __launch_bounds__(256) void m2_kernel(
    const float* __restrict__ X2, const float* __restrict__ core3,
    float* __restrict__ m2t)
{
  const int tid = threadIdx.x;
  const int n0 = blockIdx.x * 32;
  const int n = tid & 31, q = tid >> 5;
  float acc[4] = {};
  for (int d = 0; d < D; ++d) {
    float x = X2[(size_t)d * B + n0 + n];
#pragma unroll
    for (int cc = 0; cc < 4; ++cc)
      acc[cc] += core3[(q * 4 + cc) * D + d] * x;
  }
#pragma unroll
  for (int cc = 0; cc < 4; ++cc)
    m2t[(size_t)(n0 + n) * R + q * 4 + cc] = acc[cc];
}

// ---------------------------------------------------------------------------
// K5: per-sample chain on transposed M: one wave per sample.
//   lane l holds rows l*16..l*16+15; pair (2g,2g+1) reduces to t[g]/z[g].
// ---------------------------------------------------------------------------
__global__ __launch_bounds__(256) void chain_kernel(
    const ushort_t* __restrict__ Mt, const float* __restrict__ m2t,
    float* __restrict__ zt)
{
  __shared__ float ts[4][R];
  const int tid = threadIdx.x;
  const int lane = tid & 63, w = tid >> 6;
  const int h = lane & 1, g = lane >> 1;
  const ushort_t* __restrict__ Mt0 = Mt;                    // [n][1024]
  const ushort_t* __restrict__ Mt1 = Mt + (size_t)B * AB;
  const int nb = blockIdx.x * 8 + w * 2;

#pragma unroll
  for (int s = 0; s < 2; ++s) {
    const int n = nb + s;
    const size_t rowbase = (size_t)n * AB + lane * 16;

    // m2 segment this lane needs: m2t[n][h*16 .. h*16+15] (broadcast loads)
    float4 m2v[4];
#pragma unroll
    for (int q = 0; q < 4; ++q)
      m2v[q] = *(const float4*)&m2t[(size_t)n * R + h * 16 + q * 4];

    bf16x8 m1a = *(const bf16x8*)&Mt1[rowbase];
    bf16x8 m1b = *(const bf16x8*)&Mt1[rowbase + 8];
    bf16x8 m0a = *(const bf16x8*)&Mt0[rowbase];
    bf16x8 m0b = *(const bf16x8*)&Mt0[rowbase + 8];

    float m2f[16] = {m2v[0].x, m2v[0].y, m2v[0].z, m2v[0].w,
                     m2v[1].x, m2v[1].y, m2v[1].z, m2v[1].w,
                     m2v[2].x, m2v[2].y, m2v[2].z, m2v[2].w,
                     m2v[3].x, m2v[3].y, m2v[3].z, m2v[3].w};
    float pt = 0.f;
#pragma unroll
    for (int k = 0; k < 8; ++k) pt += bf2f((ushort_t)m1a[k]) * m2f[k];
#pragma unroll
    for (int k = 0; k < 8; ++k) pt += bf2f((ushort_t)m1b[k]) * m2f[8 + k];
    pt += __shfl_xor(pt, 1, 64);
    if (h == 0) ts[w][g] = pt;          // t[b] complete, b = g

    float pz = 0.f;
#pragma unroll
    for (int k = 0; k < 8; ++k) pz += bf2f((ushort_t)m0a[k]) * ts[w][h * 16 + k];
#pragma unroll
    for (int k = 0; k < 8; ++k) pz += bf2f((ushort_t)m0b[k]) * ts[w][h * 16 + 8 + k];
    pz += __shfl_xor(pz, 1, 64);
    if (h == 0) zt[(size_t)n * R + g] = pz;   // z[a], a = g
  }
}

// ---------------------------------------------------------------------------
// K6: Z[d][n] = sum_a core0[d][a] * zt[n][a]
// ---------------------------------------------------------------------------
__global__ __launch_bounds__(256) void zgemm(
    const float* __restrict__ zt, const float* __restrict__ core0,
    float* __restrict__ out)
{
  __shared__ float c0s[64][R];
  __shared__ float zs[R][132];
  const int n0 = blockIdx.x * 128, d0 = blockIdx.y * 64;
  const int tid = threadIdx.x;
#pragma unroll
  for (int i = 0; i < 4; ++i) {
    int ch = i * 256 + tid;               // 1024 float4 chunks over a
    int nr = ch >> 3, a4 = (ch & 7) * 4;
    float4 v = *(const float4*)&zt[(size_t)(n0 + nr) * R + a4];
    zs[a4 + 0][nr] = v.x; zs[a4 + 1][nr] = v.y;
    zs[a4 + 2][nr] = v.z; zs[a4 + 3][nr] = v.w;
  }
#pragma unroll
  for (int i = 0; i < 2; ++i) {
    int ch = i * 256 + tid;               // 512 float4 chunks of core0 tile
    int rr = ch >> 3, off = (ch & 7) * 4;
    *(float4*)&c0s[rr][off] = *(const float4*)&core0[(size_t)(d0 + rr) * R + off];
  }
  __syncthreads();
  const int tx = tid & 31, ty = tid >> 5;
  float acc[8][4] = {};
  for (int k = 0; k < R; ++k) {
    float4 z4 = *(const float4*)&zs[k][tx * 4];
    float zz[4] = {z4.x, z4.y, z4.z, z4.w};
#pragma unroll
    for (int i = 0; i < 8; ++i) {
      float cv = c0s[ty * 8 + i][k];
#pragma unroll
      for (int jj = 0; jj < 4; ++jj) acc[i][jj] += cv * zz[jj];
    }
  }
#pragma unroll
  for (int i = 0; i < 8; ++i) {
    float4 o = {acc[i][0], acc[i][1], acc[i][2], acc[i][3]};
    *(float4*)&out[(size_t)(d0 + ty * 8 + i) * B + n0 + tx * 4] = o;
  }
}

// ---------------------------------------------------------------------------
extern "C" void kernel_launch(void* const* d_in, const int* in_sizes, int n_in,
                              void* d_out, int out_size, void* d_ws, size_t ws_size,
                              hipStream_t stream)
{
  const float* X0    = (const float*)d_in[0];
  const float* X1    = (const float*)d_in[1];
  const float* X2    = (const float*)d_in[2];
  const float* core0 = (const float*)d_in[3];
  const float* core1 = (const float*)d_in[4];
  const float* core2 = (const float*)d_in[5];
  const float* core3 = (const float*)d_in[6];
  float* out = (float*)d_out;

  char* ws = (char*)d_ws;
  ushort_t* Apack = (ushort_t*)(ws);                        //  2 MB
  ushort_t* Xt    = (ushort_t*)(ws + (2u << 20));           //  8 MB
  ushort_t* Mt    = (ushort_t*)(ws + (10u << 20));          // 16 MB
  float*    m2t   = (float*)   (ws + (26u << 20));          // 0.5 MB
  float*    zt    = (float*)   (ws + (27u << 20));          // 0.5 MB

  hipLaunchKernelGGL(pack_cores, dim3(64), dim3(256), 0, stream, core1, core2, Apack);
  hipLaunchKernelGGL(transpose_x, dim3(64, 8, 2), dim3(256), 0, stream, X0, X1, Xt);
  hipLaunchKernelGGL(gemm_mfma, dim3(8, 32, 2), dim3(256), 0, stream, Apack, Xt, Mt);
  hipLaunchKernelGGL(m2_kernel, dim3(128), dim3(256), 0, stream, X2, core3, m2t);
  hipLaunchKernelGGL(chain_kernel, dim3(512), dim3(256), 0, stream, Mt, m2t, zt);
  hipLaunchKernelGGL(zgemm, dim3(32, 8), dim3(256), 0, stream, zt, core0, out);
}

// Round 5
// 112.260 us; speedup vs baseline: 2.8659x; 1.2467x over previous
//
#include <hip/hip_runtime.h>

#define D 512      // view dim / d_out
#define B 4096     // batch
#define R 32       // TT rank
#define AB 1024    // R*R rows of reshaped core GEMM

typedef unsigned short ushort_t;
typedef __attribute__((ext_vector_type(8))) short bf16x8;
typedef __attribute__((ext_vector_type(4))) float f32x4;

__device__ __forceinline__ ushort_t f2bf(float f) {
  uint32_t u = __builtin_bit_cast(uint32_t, f);
  u = (u + 0x7FFFu + ((u >> 16) & 1u)) >> 16;   // RNE
  return (ushort_t)u;
}
__device__ __forceinline__ float bf2f(ushort_t h) {
  uint32_t u = ((uint32_t)h) << 16;
  return __builtin_bit_cast(float, u);
}
__device__ __forceinline__ void gload_lds16(const void* g, void* lds) {
  __builtin_amdgcn_global_load_lds(
      (const __attribute__((address_space(1))) unsigned int*)g,
      (__attribute__((address_space(3))) unsigned int*)lds, 16, 0, 0);
}

// ---------------------------------------------------------------------------
// K1: prep — one flat-grid kernel:
//   bid <  1536 : transpose X_v fp32 [d][n] -> Xt bf16 [v][n][d]  (v = bid/512)
//   1536..1599  : pack core1/core2 [a][d][b] -> Apack[j][a*32+b][d]
//   1600..1607  : pack core3 [c][d] -> Apack3[128][512] (rows 32..127 zeroed)
// ---------------------------------------------------------------------------
__global__ __launch_bounds__(256) void prep(
    const float* __restrict__ X0, const float* __restrict__ X1,
    const float* __restrict__ X2, const float* __restrict__ c1,
    const float* __restrict__ c2, const float* __restrict__ c3,
    ushort_t* __restrict__ Xt, ushort_t* __restrict__ Apack,
    ushort_t* __restrict__ Apack3)
{
  __shared__ __align__(16) char smem[33280];
  const int bid = blockIdx.x, tid = threadIdx.x;

  if (bid < 1536) {
    // ---- transpose: 64x64 tile ----
    float (*T)[65] = (float(*)[65])smem;          // [64][65]
    const int v = bid / 512, tile = bid % 512;
    const float* __restrict__ X = (v == 0) ? X0 : ((v == 1) ? X1 : X2);
    ushort_t* __restrict__ O = Xt + (size_t)v * B * D;
    const int n0 = (tile & 63) * 64, d0 = (tile >> 6) * 64;
#pragma unroll
    for (int i = 0; i < 16; ++i) {
      int e = i * 256 + tid;
      T[e >> 6][e & 63] = X[(size_t)(d0 + (e >> 6)) * B + n0 + (e & 63)];
    }
    __syncthreads();
#pragma unroll
    for (int i = 0; i < 2; ++i) {
      int ch = i * 256 + tid;                // 512 chunks
      int nr = ch >> 3, dc = (ch & 7) * 8;
      ushort_t w[8];
#pragma unroll
      for (int q = 0; q < 8; ++q) w[q] = f2bf(T[dc + q][nr]);
      *(bf16x8*)&O[(size_t)(n0 + nr) * D + d0 + dc] = *(bf16x8*)w;
    }
  } else if (bid < 1600) {
    // ---- pack core1/core2 ----
    ushort_t (*T)[D + 8] = (ushort_t(*)[D + 8])smem;   // [32][520]
    const int ja = bid - 1536, j = ja >> 5, a = ja & 31;
    const float* __restrict__ c = j ? c2 : c1;
#pragma unroll
    for (int i = 0; i < 64; ++i) {
      int e = i * 256 + tid;                 // e = d*32 + b, coalesced source
      T[e & 31][e >> 5] = f2bf(c[(size_t)a * (D * R) + e]);
    }
    __syncthreads();
#pragma unroll
    for (int i = 0; i < 8; ++i) {
      int ch = i * 256 + tid;                // 2048 16B chunks
      int b = ch >> 6, off = (ch & 63) * 8;
      ushort_t w[8];
#pragma unroll
      for (int q = 0; q < 8; ++q) w[q] = T[b][off + q];
      *(bf16x8*)&Apack[((size_t)j * AB + a * 32 + b) * D + off] = *(bf16x8*)w;
    }
  } else {
    // ---- pack core3: 16 rows per block ----
    const int r0 = (bid - 1600) * 16;
#pragma unroll
    for (int i = 0; i < 4; ++i) {
      int ch = i * 256 + tid;                // 1024 8-elem chunks = 16x512
      int rr = r0 + (ch >> 6), off = (ch & 63) * 8;
      ushort_t w[8];
      if (rr < R) {
#pragma unroll
        for (int q = 0; q < 8; ++q) w[q] = f2bf(c3[(size_t)rr * D + off + q]);
      } else {
#pragma unroll
        for (int q = 0; q < 8; ++q) w[q] = 0;
      }
      *(bf16x8*)&Apack3[(size_t)rr * D + off] = *(bf16x8*)w;
    }
  }
}

// ---------------------------------------------------------------------------
// K2: MFMA GEMM, 3 "views":
//   bid<512 : Mt_j[n][row] = sum_d Xt_j[n][d] * Apack_j[row][d], j=bid>>8
//   bid>=512: Mt2[n][c]    = sum_d Xt_2[n][d] * Apack3[c][d]   (32 blocks)
// 128x128 tile, BK=32, 4 waves, dbuf global_load_lds, XOR-swizzled LDS,
// LDS-staged epilogue for coalesced [n][row] stores.
// ---------------------------------------------------------------------------
__global__ __launch_bounds__(256) void gemm_mfma(
    const ushort_t* __restrict__ Apack, const ushort_t* __restrict__ Apack3,
    const ushort_t* __restrict__ Xt, ushort_t* __restrict__ Mt,
    ushort_t* __restrict__ Mt2)
{
  __shared__ __align__(16) ushort_t smem[17408];   // 34.8 KB
  ushort_t* As0 = smem;            // Xt tile buf0: [128 n][32 k] swizzled
  ushort_t* As1 = smem + 4096;
  ushort_t* Bs0 = smem + 8192;     // core tile
  ushort_t* Bs1 = smem + 12288;

  const int bid = blockIdx.x;
  int j, rb, nb, ldc;
  const ushort_t *Ag, *Bg;
  ushort_t* C;
  if (bid < 512) {
    j = bid >> 8; int w = bid & 255; rb = w >> 5; nb = w & 31;
    Ag = Xt + (size_t)j * B * D;
    Bg = Apack + (size_t)j * AB * D;
    C  = Mt + (size_t)j * B * AB;  ldc = AB;
  } else {
    j = 2; rb = 0; nb = bid - 512;
    Ag = Xt + (size_t)2 * B * D;
    Bg = Apack3;
    C  = Mt2;  ldc = 128;
  }

  const int tid = threadIdx.x;
  const int lane = tid & 63, wid = tid >> 6;
  const int wr = wid >> 1, wc = wid & 1;
  const int nBase = nb * 128;   // over B=4096
  const int rBase = rb * 128;   // over row dim

  // staging map: 16B unit t -> LDS (row=t>>2, slot u'=t&3); src u = u'^(row&3)
  const int t0 = wid * 128 + lane, t1 = t0 + 64;
  const int r0 = t0 >> 2, u0 = (t0 & 3) ^ (r0 & 3);
  const int r1 = t1 >> 2, u1 = (t1 & 3) ^ (r1 & 3);
  const ushort_t* gA0 = Ag + (size_t)(nBase + r0) * D + u0 * 8;
  const ushort_t* gA1 = Ag + (size_t)(nBase + r1) * D + u1 * 8;
  const ushort_t* gB0 = Bg + (size_t)(rBase + r0) * D + u0 * 8;
  const ushort_t* gB1 = Bg + (size_t)(rBase + r1) * D + u1 * 8;
  const int lq0 = wid * 1024, lq1 = wid * 1024 + 512;   // element offsets

  // frag read offsets: logical (row, u=lane>>4) -> slot u^(row&3)
  int aoff[4], boff[4];
#pragma unroll
  for (int m = 0; m < 4; ++m) {
    int row = wr * 64 + m * 16 + (lane & 15);
    aoff[m] = row * 32 + (((lane >> 4) ^ (row & 3)) * 8);
  }
#pragma unroll
  for (int n = 0; n < 4; ++n) {
    int col = wc * 64 + n * 16 + (lane & 15);
    boff[n] = col * 32 + (((lane >> 4) ^ (col & 3)) * 8);
  }

  f32x4 acc[4][4] = {};

  auto stage = [&](ushort_t* Asb, ushort_t* Bsb, int k0) {
    gload_lds16(gA0 + k0, Asb + lq0);
    gload_lds16(gA1 + k0, Asb + lq1);
    gload_lds16(gB0 + k0, Bsb + lq0);
    gload_lds16(gB1 + k0, Bsb + lq1);
  };
  auto compute = [&](const ushort_t* Asb, const ushort_t* Bsb) {
    bf16x8 a[4], b[4];
#pragma unroll
    for (int m = 0; m < 4; ++m) a[m] = *(const bf16x8*)&Asb[aoff[m]];
#pragma unroll
    for (int n = 0; n < 4; ++n) b[n] = *(const bf16x8*)&Bsb[boff[n]];
#pragma unroll
    for (int m = 0; m < 4; ++m)
#pragma unroll
      for (int n = 0; n < 4; ++n)
        acc[m][n] = __builtin_amdgcn_mfma_f32_16x16x32_bf16(a[m], b[n], acc[m][n], 0, 0, 0);
  };

  stage(As0, Bs0, 0);
  __syncthreads();
#pragma unroll 1
  for (int kp = 0; kp < 8; ++kp) {
    stage(As1, Bs1, kp * 64 + 32);        // prefetch odd tile
    compute(As0, Bs0);
    __syncthreads();
    if (kp < 7) stage(As0, Bs0, kp * 64 + 64);  // prefetch next even tile
    compute(As1, Bs1);
    __syncthreads();
  }

  // epilogue: acc -> LDS tile T[128 n][128 row] (pad 8) -> coalesced stores
#define TLD 136
  ushort_t* T = smem;
  const int qn = (lane >> 4) << 2;
#pragma unroll
  for (int m = 0; m < 4; ++m)
#pragma unroll
    for (int nn = 0; nn < 4; ++nn) {
      int nl = wr * 64 + m * 16 + qn;
      int rl = wc * 64 + nn * 16 + (lane & 15);
#pragma unroll
      for (int r = 0; r < 4; ++r)
        T[(nl + r) * TLD + rl] = f2bf(acc[m][nn][r]);
    }
  __syncthreads();
#pragma unroll
  for (int i = 0; i < 8; ++i) {
    int nl = i * 16 + (tid >> 4);
    int rl = (tid & 15) * 8;
    bf16x8 v = *(const bf16x8*)&T[nl * TLD + rl];
    *(bf16x8*)&C[(size_t)(nBase + nl) * ldc + rBase + rl] = v;
  }
}

// ---------------------------------------------------------------------------
// K3: per-sample chain on transposed M: one wave per sample.
//   lane l holds rows l*16..l*16+15; pair (2g,2g+1) reduces to t[g]/z[g].
//   m2 read from Mt2[n][0..31] (bf16).
// ---------------------------------------------------------------------------
__global__ __launch_bounds__(256) void chain_kernel(
    const ushort_t* __restrict__ Mt, const ushort_t* __restrict__ Mt2,
    float* __restrict__ zt)
{
  __shared__ float ts[4][R];
  const int tid = threadIdx.x;
  const int lane = tid & 63, w = tid >> 6;
  const int h = lane & 1, g = lane >> 1;
  const ushort_t* __restrict__ Mt0 = Mt;                    // [n][1024]
  const ushort_t* __restrict__ Mt1 = Mt + (size_t)B * AB;
  const int nb = blockIdx.x * 8 + w * 2;

#pragma unroll
  for (int s = 0; s < 2; ++s) {
    const int n = nb + s;
    const size_t rowbase = (size_t)n * AB + lane * 16;

    // m2 segment this lane needs: Mt2[n][h*16 .. h*16+15] (bf16)
    bf16x8 m2a = *(const bf16x8*)&Mt2[(size_t)n * 128 + h * 16];
    bf16x8 m2b = *(const bf16x8*)&Mt2[(size_t)n * 128 + h * 16 + 8];

    bf16x8 m1a = *(const bf16x8*)&Mt1[rowbase];
    bf16x8 m1b = *(const bf16x8*)&Mt1[rowbase + 8];
    bf16x8 m0a = *(const bf16x8*)&Mt0[rowbase];
    bf16x8 m0b = *(const bf16x8*)&Mt0[rowbase + 8];

    float pt = 0.f;
#pragma unroll
    for (int k = 0; k < 8; ++k) pt += bf2f((ushort_t)m1a[k]) * bf2f((ushort_t)m2a[k]);
#pragma unroll
    for (int k = 0; k < 8; ++k) pt += bf2f((ushort_t)m1b[k]) * bf2f((ushort_t)m2b[k]);
    pt += __shfl_xor(pt, 1, 64);
    if (h == 0) ts[w][g] = pt;          // t[b] complete, b = g

    float pz = 0.f;
#pragma unroll
    for (int k = 0; k < 8; ++k) pz += bf2f((ushort_t)m0a[k]) * ts[w][h * 16 + k];
#pragma unroll
    for (int k = 0; k < 8; ++k) pz += bf2f((ushort_t)m0b[k]) * ts[w][h * 16 + 8 + k];
    pz += __shfl_xor(pz, 1, 64);
    if (h == 0) zt[(size_t)n * R + g] = pz;   // z[a], a = g
  }
}

// ---------------------------------------------------------------------------
// K4: Z[d][n] = sum_a core0[d][a] * zt[n][a]
// ---------------------------------------------------------------------------
__global__ __launch_bounds__(256) void zgemm(
    const float* __restrict__ zt, const float* __restrict__ core0,
    float* __restrict__ out)
{
  __shared__ float c0s[64][R];
  __shared__ float zs[R][132];
  const int n0 = blockIdx.x * 128, d0 = blockIdx.y * 64;
  const int tid = threadIdx.x;
#pragma unroll
  for (int i = 0; i < 4; ++i) {
    int ch = i * 256 + tid;               // 1024 float4 chunks over a
    int nr = ch >> 3, a4 = (ch & 7) * 4;
    float4 v = *(const float4*)&zt[(size_t)(n0 + nr) * R + a4];
    zs[a4 + 0][nr] = v.x; zs[a4 + 1][nr] = v.y;
    zs[a4 + 2][nr] = v.z; zs[a4 + 3][nr] = v.w;
  }
#pragma unroll
  for (int i = 0; i < 2; ++i) {
    int ch = i * 256 + tid;               // 512 float4 chunks of core0 tile
    int rr = ch >> 3, off = (ch & 7) * 4;
    *(float4*)&c0s[rr][off] = *(const float4*)&core0[(size_t)(d0 + rr) * R + off];
  }
  __syncthreads();
  const int tx = tid & 31, ty = tid >> 5;
  float acc[8][4] = {};
  for (int k = 0; k < R; ++k) {
    float4 z4 = *(const float4*)&zs[k][tx * 4];
    float zz[4] = {z4.x, z4.y, z4.z, z4.w};
#pragma unroll
    for (int i = 0; i < 8; ++i) {
      float cv = c0s[ty * 8 + i][k];
#pragma unroll
      for (int jj = 0; jj < 4; ++jj) acc[i][jj] += cv * zz[jj];
    }
  }
#pragma unroll
  for (int i = 0; i < 8; ++i) {
    float4 o = {acc[i][0], acc[i][1], acc[i][2], acc[i][3]};
    *(float4*)&out[(size_t)(d0 + ty * 8 + i) * B + n0 + tx * 4] = o;
  }
}

// ---------------------------------------------------------------------------
extern "C" void kernel_launch(void* const* d_in, const int* in_sizes, int n_in,
                              void* d_out, int out_size, void* d_ws, size_t ws_size,
                              hipStream_t stream)
{
  const float* X0    = (const float*)d_in[0];
  const float* X1    = (const float*)d_in[1];
  const float* X2    = (const float*)d_in[2];
  const float* core0 = (const float*)d_in[3];
  const float* core1 = (const float*)d_in[4];
  const float* core2 = (const float*)d_in[5];
  const float* core3 = (const float*)d_in[6];
  float* out = (float*)d_out;

  char* ws = (char*)d_ws;
  ushort_t* Apack  = (ushort_t*)(ws);                       //  2 MiB @ 0
  ushort_t* Apack3 = (ushort_t*)(ws + (2u  << 20));         //  128 KiB
  ushort_t* Xt     = (ushort_t*)(ws + (4u  << 20));         //  12 MiB (3 views)
  ushort_t* Mt     = (ushort_t*)(ws + (16u << 20));         //  16 MiB
  ushort_t* Mt2    = (ushort_t*)(ws + (32u << 20));         //   1 MiB
  float*    zt     = (float*)   (ws + (33u << 20));         //  0.5 MiB

  hipLaunchKernelGGL(prep, dim3(1608), dim3(256), 0, stream,
                     X0, X1, X2, core1, core2, core3, Xt, Apack, Apack3);
  hipLaunchKernelGGL(gemm_mfma, dim3(544), dim3(256), 0, stream,
                     Apack, Apack3, Xt, Mt, Mt2);
  hipLaunchKernelGGL(chain_kernel, dim3(512), dim3(256), 0, stream, Mt, Mt2, zt);
  hipLaunchKernelGGL(zgemm, dim3(32, 8), dim3(256), 0, stream, zt, core0, out);
}